// Round 9
// baseline (1143.316 us; speedup 1.0000x reference)
//
#include <hip/hip_runtime.h>

// VALSTM: B=256, T=512, IN=64, HS=128, gates=512.
// 16 blocks x 512 threads (8 waves). Block owns 16 batch rows for all T.
// Weights in registers as bf16 B-fragments, pre-scaled by log2e factors.
// Per step (3 raw lgkmcnt-only barriers):
//   A: [w<4: attn pre x@Wa + hc@Ua (depth-2 chains) -> tanh -> ta]
//      [w>=4: U-GEMM (fills their idle A; frees B issue for producers)] bar2
//   B: [w<4 ONLY: Va^T-GEMM -> exp2 -> u=e*x -> S4 partials -> U-GEMM] bar3
//   C: [all: W-GEMM on u, fold cross-wave rinv, LSTM -> hc;
//       x staging at C-tail (precise vmcnt; r7 lesson)]               bar1
// r6 lesson: softmax denom spans 4 producer waves -> S4 + post-GEMM fold.
// r8: consumer-U->A (B = producer-only issue), depth-2 MFMA chains in A,
//     v_perm_b32 pack2.

#define TSEQ 512
#define NB   256
#define DIN  64
#define DHS  128
#define LOG2E 1.44269504f

typedef short bf16x8 __attribute__((ext_vector_type(8)));
typedef float f32x4  __attribute__((ext_vector_type(4)));
typedef unsigned long long u64;

#define SWZ(off, row) ((off) ^ (((row) & 7) << 4))

__device__ __forceinline__ void bar_lds() {
  asm volatile("s_waitcnt lgkmcnt(0)\n\ts_barrier" ::: "memory");
}

__device__ __forceinline__ float fexp2(float x) { return __builtin_amdgcn_exp2f(x); }
__device__ __forceinline__ float frcp(float x)  { return __builtin_amdgcn_rcpf(x); }
// inputs pre-scaled: x' = log2e*x (sig3), x' = 2*log2e*x (tanh4)
__device__ __forceinline__ float sig3(float x)  { return frcp(1.0f + fexp2(-x)); }
__device__ __forceinline__ float tanh4(float x) { return 1.0f - 2.0f * frcp(1.0f + fexp2(x)); }
__device__ __forceinline__ float tanh5(float y) { return 1.0f - 2.0f * frcp(1.0f + fexp2(2.0f * LOG2E * y)); }

__device__ __forceinline__ unsigned short f2bf(float f) {
  return (unsigned short)((__float_as_uint(f) + 0x8000u) >> 16);
}
// pack two rounded bf16 halves in 3 VALU ops via v_perm_b32
__device__ __forceinline__ unsigned int pack2(float a, float b) {
  return __builtin_amdgcn_perm(__float_as_uint(b) + 0x8000u,
                               __float_as_uint(a) + 0x8000u,
                               0x07060302u);
}
__device__ __forceinline__ float bf2f(unsigned short u) {
  return __uint_as_float(((unsigned int)u) << 16);
}

__global__ __launch_bounds__(512, 2) void valstm_kernel(
    const float* __restrict__ X,  const float* __restrict__ W,  const float* __restrict__ U,
    const float* __restrict__ bias, const float* __restrict__ Wa, const float* __restrict__ Ua,
    const float* __restrict__ ba, const float* __restrict__ Va,
    const float* __restrict__ fcw, const float* __restrict__ fcb,
    float* __restrict__ out)
{
  const int tid = threadIdx.x;
  const int w   = tid >> 6;
  const int l   = tid & 63;
  const int lo  = l & 15;
  const int hi  = l >> 4;
  const int b0  = blockIdx.x * 16;

  // ---- LDS ----
  __shared__ __align__(16) unsigned short hc[16 * 256];      // h|c bf16, stride 512B
  __shared__ __align__(16) unsigned short xbuf2[2][16 * 64]; // x bf16 dbuf, stride 128B
  __shared__ __align__(16) unsigned short ta[16 * 64];       // tanh(attn pre), stride 128B
  __shared__ __align__(16) unsigned short ubuf[16 * 64];     // e*x bf16 (unnormalized), stride 128B
  __shared__ __align__(16) float S4[64];                     // [row][wave] exp partial sums
  __shared__ __align__(16) float hf[16 * 128];               // final-step h f32

  // ---- gate weights as B-fragments, pre-scaled by activation log2e factors ----
  const float sgate[4] = {LOG2E, LOG2E, 2.0f * LOG2E, LOG2E};  // i,f sig | g tanh | o sig
  bf16x8 Uf[4][4];
  bf16x8 Wf[4][2];
  float  biasr[4];
  const int hid = 16 * w + lo;
  #pragma unroll
  for (int g = 0; g < 4; ++g) {
    const int j = g * 128 + hid;
    const float s = sgate[g];
    biasr[g] = bias[j] * s;
    #pragma unroll
    for (int kt = 0; kt < 4; ++kt) {
      bf16x8 v;
      #pragma unroll
      for (int e = 0; e < 8; ++e) { const int k = kt * 32 + hi * 8 + e; v[e] = (short)f2bf(U[k * 512 + j] * s); }
      Uf[g][kt] = v;
    }
    #pragma unroll
    for (int kt = 0; kt < 2; ++kt) {
      bf16x8 v;
      #pragma unroll
      for (int e = 0; e < 8; ++e) { const int k = kt * 32 + hi * 8 + e; v[e] = (short)f2bf(W[k * 512 + j] * s); }
      Wf[g][kt] = v;
    }
  }

  // ---- attention weights (waves 0..3): Wa/Ua/ba *2log2e (tanh), Va *log2e (exp2) ----
  bf16x8 Uaf[8], Waf[2], Vaf[2];
  float  bar = 0.0f;
  if (w < 4) {
    const int ja = 16 * w + lo;
    const float SA = 2.0f * LOG2E;
    bar = ba[ja] * SA;
    #pragma unroll
    for (int kt = 0; kt < 8; ++kt) {
      bf16x8 v;
      #pragma unroll
      for (int e = 0; e < 8; ++e) { const int k = kt * 32 + hi * 8 + e; v[e] = (short)f2bf(Ua[k * 64 + ja] * SA); }
      Uaf[kt] = v;
    }
    #pragma unroll
    for (int kt = 0; kt < 2; ++kt) {
      bf16x8 v;
      #pragma unroll
      for (int e = 0; e < 8; ++e) { const int k = kt * 32 + hi * 8 + e; v[e] = (short)f2bf(Wa[k * 64 + ja] * SA); }
      Waf[kt] = v;
    }
    #pragma unroll
    for (int kt = 0; kt < 2; ++kt) {
      bf16x8 v;
      #pragma unroll
      for (int e = 0; e < 8; ++e) { const int k = kt * 32 + hi * 8 + e; v[e] = (short)f2bf(Va[k * 64 + ja] * LOG2E); }
      Vaf[kt] = v;
    }
  }

  // ---- hoisted swizzled LDS byte-offsets ----
  int haf_off[4], caf_off[4], xa_off[2];
  #pragma unroll
  for (int kt = 0; kt < 4; ++kt) {
    haf_off[kt] = SWZ(lo * 512 + (kt * 32 + hi * 8) * 2, lo);
    caf_off[kt] = SWZ(lo * 512 + ((kt + 4) * 32 + hi * 8) * 2, lo);
  }
  #pragma unroll
  for (int kt = 0; kt < 2; ++kt)
    xa_off[kt] = SWZ(lo * 128 + (kt * 32 + hi * 8) * 2, lo);   // x, ta, u fragment reads
  int ta_st[4], hc_h[4], hc_c[4];
  #pragma unroll
  for (int ri = 0; ri < 4; ++ri) {
    const int rr = hi * 4 + ri;
    ta_st[ri] = SWZ(rr * 128 + (16 * w + lo) * 2, rr);
    hc_h[ri]  = SWZ(rr * 512 + hid * 2, rr);
    hc_c[ri]  = SWZ(rr * 512 + (128 + hid) * 2, rr);
  }
  const int uq_off = SWZ(lo * 128 + (16 * w + hi * 4) * 2, lo); // producer u/x slots

  // ---- zero h,c ----
  *(f32x4*)((char*)hc + tid * 16) = (f32x4){0.f, 0.f, 0.f, 0.f};

  // ---- x staging (all threads, 2 cols each, C-tail placement) ----
  const int xr = tid >> 5;
  const int xc = (tid & 31) * 2;
  const int xst_off = SWZ(xr * 128 + xc * 2, xr);
  const float* xptr = X + (size_t)(b0 + xr) * TSEQ * DIN + xc;
  {
    const float2 v0 = *(const float2*)(xptr + 0 * DIN);
    *(unsigned int*)((char*)xbuf2[0] + xst_off) = pack2(v0.x, v0.y);
  }
  float2 xf = *(const float2*)(xptr + 1 * DIN);

  float cst[4] = {0.f, 0.f, 0.f, 0.f};

  float* outY  = out;
  float* outHS = out + 256;
  float* outHT = out + 256 + (size_t)NB * TSEQ * DHS;
  float* outCT = outHT + NB * DHS;
  float* outAL = outCT + NB * DHS;

  float* hsP[4];
  #pragma unroll
  for (int ri = 0; ri < 4; ++ri)
    hsP[ri] = outHS + (size_t)(b0 + hi * 4 + ri) * TSEQ * DHS + hid;

  bar_lds();

  #pragma unroll 1
  for (int t = 0; t < TSEQ - 1; ++t) {
    const int xoff = (t & 1) << 11;

    bf16x8 haf[4];
    #pragma unroll
    for (int kt = 0; kt < 4; ++kt)
      haf[kt] = *(const bf16x8*)((const char*)hc + haf_off[kt]);

    f32x4 accU[4];

    // ---- A: producers attn pre (depth-2 chains); consumers U-GEMM ----
    if (w >= 4) {
      #pragma unroll
      for (int g = 0; g < 4; ++g) {
        accU[g] = (f32x4){biasr[g], biasr[g], biasr[g], biasr[g]};
        #pragma unroll
        for (int kt = 0; kt < 4; ++kt)
          accU[g] = __builtin_amdgcn_mfma_f32_16x16x32_bf16(haf[kt], Uf[g][kt], accU[g], 0, 0, 0);
      }
    } else {
      __builtin_amdgcn_s_setprio(1);
      f32x4 aa  = (f32x4){bar, bar, bar, bar};
      f32x4 ah0 = (f32x4){0.f, 0.f, 0.f, 0.f};
      f32x4 ah1 = (f32x4){0.f, 0.f, 0.f, 0.f};
      f32x4 ac0 = (f32x4){0.f, 0.f, 0.f, 0.f};
      f32x4 ac1 = (f32x4){0.f, 0.f, 0.f, 0.f};
      #pragma unroll
      for (int kt = 0; kt < 2; ++kt) {
        bf16x8 xa = *(const bf16x8*)((const char*)xbuf2[0] + xoff + xa_off[kt]);
        aa = __builtin_amdgcn_mfma_f32_16x16x32_bf16(xa, Waf[kt], aa, 0, 0, 0);
      }
      ah0 = __builtin_amdgcn_mfma_f32_16x16x32_bf16(haf[0], Uaf[0], ah0, 0, 0, 0);
      ah0 = __builtin_amdgcn_mfma_f32_16x16x32_bf16(haf[1], Uaf[1], ah0, 0, 0, 0);
      ah1 = __builtin_amdgcn_mfma_f32_16x16x32_bf16(haf[2], Uaf[2], ah1, 0, 0, 0);
      ah1 = __builtin_amdgcn_mfma_f32_16x16x32_bf16(haf[3], Uaf[3], ah1, 0, 0, 0);
      {
        bf16x8 ca0 = *(const bf16x8*)((const char*)hc + caf_off[0]);
        bf16x8 ca1 = *(const bf16x8*)((const char*)hc + caf_off[1]);
        ac0 = __builtin_amdgcn_mfma_f32_16x16x32_bf16(ca0, Uaf[4], ac0, 0, 0, 0);
        ac0 = __builtin_amdgcn_mfma_f32_16x16x32_bf16(ca1, Uaf[5], ac0, 0, 0, 0);
        bf16x8 ca2 = *(const bf16x8*)((const char*)hc + caf_off[2]);
        bf16x8 ca3 = *(const bf16x8*)((const char*)hc + caf_off[3]);
        ac1 = __builtin_amdgcn_mfma_f32_16x16x32_bf16(ca2, Uaf[6], ac1, 0, 0, 0);
        ac1 = __builtin_amdgcn_mfma_f32_16x16x32_bf16(ca3, Uaf[7], ac1, 0, 0, 0);
      }
      const f32x4 pre = ((aa + ah0) + (ah1 + ac0)) + ac1;   // pre-scaled by 2log2e
      #pragma unroll
      for (int ri = 0; ri < 4; ++ri)
        *(unsigned short*)((char*)ta + ta_st[ri]) = f2bf(tanh4(pre[ri]));
    }
    bar_lds();  // bar2: ta ready

    // ---- B: producers ONLY — Va->exp2->u + S4 partials + their U-GEMM ----
    if (w < 4) {
      f32x4 av = (f32x4){0.f, 0.f, 0.f, 0.f};
      #pragma unroll
      for (int kt = 0; kt < 2; ++kt) {
        bf16x8 tf = *(const bf16x8*)((const char*)ta + xa_off[kt]);
        av = __builtin_amdgcn_mfma_f32_16x16x32_bf16(Vaf[kt], tf, av, 0, 0, 0);
      }
      f32x4 ev;
      #pragma unroll
      for (int ri = 0; ri < 4; ++ri) ev[ri] = fexp2(av[ri]);   // Va pre-scaled
      const u64 xq = *(const u64*)((const char*)xbuf2[0] + xoff + uq_off);
      const unsigned int p0 = pack2(ev[0] * bf2f((unsigned short)xq),
                                    ev[1] * bf2f((unsigned short)(xq >> 16)));
      const unsigned int p1 = pack2(ev[2] * bf2f((unsigned short)(xq >> 32)),
                                    ev[3] * bf2f((unsigned short)(xq >> 48)));
      *(u64*)((char*)ubuf + uq_off) = (u64)p0 | ((u64)p1 << 32);
      float ps = ev[0] + ev[1] + ev[2] + ev[3];
      ps += __shfl_xor(ps, 16);
      ps += __shfl_xor(ps, 32);
      if (hi == 0) S4[lo * 4 + w] = ps;   // wave partial (16 of 64 cols)
      #pragma unroll
      for (int g = 0; g < 4; ++g) {
        accU[g] = (f32x4){biasr[g], biasr[g], biasr[g], biasr[g]};
        #pragma unroll
        for (int kt = 0; kt < 4; ++kt)
          accU[g] = __builtin_amdgcn_mfma_f32_16x16x32_bf16(haf[kt], Uf[g][kt], accU[g], 0, 0, 0);
      }
      __builtin_amdgcn_s_setprio(0);
    }
    bar_lds();  // bar3: u + S4 ready

    // ---- C: W-GEMM on u, fold cross-wave rinv, LSTM update ----
    f32x4 accW[4];
    #pragma unroll
    for (int g = 0; g < 4; ++g) accW[g] = (f32x4){0.f, 0.f, 0.f, 0.f};
    #pragma unroll
    for (int kt = 0; kt < 2; ++kt) {
      const bf16x8 uf = *(const bf16x8*)((const char*)ubuf + xa_off[kt]);
      #pragma unroll
      for (int g = 0; g < 4; ++g)
        accW[g] = __builtin_amdgcn_mfma_f32_16x16x32_bf16(uf, Wf[g][kt], accW[g], 0, 0, 0);
    }
    float rinv_[4];
    #pragma unroll
    for (int ri = 0; ri < 4; ++ri) {
      const f32x4 s4v = *(const f32x4*)(S4 + (hi * 4 + ri) * 4);
      rinv_[ri] = frcp(s4v[0] + s4v[1] + s4v[2] + s4v[3]);
    }
    #pragma unroll
    for (int ri = 0; ri < 4; ++ri) {
      const float iv = sig3(accW[0][ri] * rinv_[ri] + accU[0][ri]);
      const float fv = sig3(accW[1][ri] * rinv_[ri] + accU[1][ri]);
      const float gv = tanh4(accW[2][ri] * rinv_[ri] + accU[2][ri]);
      const float ov = sig3(accW[3][ri] * rinv_[ri] + accU[3][ri]);
      const float cn = fv * cst[ri] + iv * gv;
      const float hv = ov * tanh5(cn);
      cst[ri] = cn;
      *(unsigned short*)((char*)hc + hc_h[ri]) = f2bf(hv);
      *(unsigned short*)((char*)hc + hc_c[ri]) = f2bf(cn);
      *hsP[ri] = hv;                      // fire-and-forget
      hsP[ri] += DHS;
    }

    // ---- stage x(t+1), prefetch x(min(t+2, T-1)) — C-tail, precise vmcnt ----
    {
      *(unsigned int*)((char*)xbuf2[0] + (((t + 1) & 1) << 11) + xst_off) = pack2(xf.x, xf.y);
      const int tn = (t + 2 < TSEQ) ? t + 2 : TSEQ - 1;
      xf = *(const float2*)(xptr + tn * DIN);
    }
    bar_lds();  // bar1
  }

  // ==== peeled final step t = TSEQ-1 (K8 layout, runs once) ====
  {
    const int xoff = ((TSEQ - 1) & 1) << 11;

    bf16x8 haf[4];
    #pragma unroll
    for (int kt = 0; kt < 4; ++kt)
      haf[kt] = *(const bf16x8*)((const char*)hc + haf_off[kt]);

    if (w < 4) {
      f32x4 aa = (f32x4){bar, bar, bar, bar};
      f32x4 ah = (f32x4){0.f, 0.f, 0.f, 0.f};
      f32x4 ac = (f32x4){0.f, 0.f, 0.f, 0.f};
      #pragma unroll
      for (int kt = 0; kt < 2; ++kt) {
        bf16x8 xa = *(const bf16x8*)((const char*)xbuf2[0] + xoff + xa_off[kt]);
        aa = __builtin_amdgcn_mfma_f32_16x16x32_bf16(xa, Waf[kt], aa, 0, 0, 0);
      }
      #pragma unroll
      for (int kt = 0; kt < 4; ++kt)
        ah = __builtin_amdgcn_mfma_f32_16x16x32_bf16(haf[kt], Uaf[kt], ah, 0, 0, 0);
      #pragma unroll
      for (int kt = 0; kt < 4; ++kt) {
        bf16x8 ca = *(const bf16x8*)((const char*)hc + caf_off[kt]);
        ac = __builtin_amdgcn_mfma_f32_16x16x32_bf16(ca, Uaf[kt + 4], ac, 0, 0, 0);
      }
      const f32x4 pre = aa + ah + ac;
      #pragma unroll
      for (int ri = 0; ri < 4; ++ri)
        *(unsigned short*)((char*)ta + ta_st[ri]) = f2bf(tanh4(pre[ri]));
    }
    bar_lds();

    f32x4 evP = (f32x4){0.f, 0.f, 0.f, 0.f};
    if (w < 4) {
      f32x4 av = (f32x4){0.f, 0.f, 0.f, 0.f};
      #pragma unroll
      for (int kt = 0; kt < 2; ++kt) {
        bf16x8 tf = *(const bf16x8*)((const char*)ta + xa_off[kt]);
        av = __builtin_amdgcn_mfma_f32_16x16x32_bf16(Vaf[kt], tf, av, 0, 0, 0);
      }
      #pragma unroll
      for (int ri = 0; ri < 4; ++ri) evP[ri] = fexp2(av[ri]);
      const u64 xq = *(const u64*)((const char*)xbuf2[0] + xoff + uq_off);
      const unsigned int p0 = pack2(evP[0] * bf2f((unsigned short)xq),
                                    evP[1] * bf2f((unsigned short)(xq >> 16)));
      const unsigned int p1 = pack2(evP[2] * bf2f((unsigned short)(xq >> 32)),
                                    evP[3] * bf2f((unsigned short)(xq >> 48)));
      *(u64*)((char*)ubuf + uq_off) = (u64)p0 | ((u64)p1 << 32);
      float ps = evP[0] + evP[1] + evP[2] + evP[3];
      ps += __shfl_xor(ps, 16);
      ps += __shfl_xor(ps, 32);
      if (hi == 0) S4[lo * 4 + w] = ps;
    }
    f32x4 accU[4];
    #pragma unroll
    for (int g = 0; g < 4; ++g) {
      accU[g] = (f32x4){biasr[g], biasr[g], biasr[g], biasr[g]};
      #pragma unroll
      for (int kt = 0; kt < 4; ++kt)
        accU[g] = __builtin_amdgcn_mfma_f32_16x16x32_bf16(haf[kt], Uf[g][kt], accU[g], 0, 0, 0);
    }
    bar_lds();

    // alpha output: cross-wave rinv for batch row lo
    if (w < 4) {
      const f32x4 s4v = *(const f32x4*)(S4 + lo * 4);
      const float rA = frcp(s4v[0] + s4v[1] + s4v[2] + s4v[3]);
      *(f32x4*)(outAL + (b0 + lo) * 64 + 16 * w + hi * 4) =
          (f32x4){evP[0] * rA, evP[1] * rA, evP[2] * rA, evP[3] * rA};
    }

    f32x4 accW[4];
    #pragma unroll
    for (int g = 0; g < 4; ++g) accW[g] = (f32x4){0.f, 0.f, 0.f, 0.f};
    #pragma unroll
    for (int kt = 0; kt < 2; ++kt) {
      const bf16x8 uf = *(const bf16x8*)((const char*)ubuf + xa_off[kt]);
      #pragma unroll
      for (int g = 0; g < 4; ++g)
        accW[g] = __builtin_amdgcn_mfma_f32_16x16x32_bf16(uf, Wf[g][kt], accW[g], 0, 0, 0);
    }
    float rinv_[4];
    #pragma unroll
    for (int ri = 0; ri < 4; ++ri) {
      const f32x4 s4v = *(const f32x4*)(S4 + (hi * 4 + ri) * 4);
      rinv_[ri] = frcp(s4v[0] + s4v[1] + s4v[2] + s4v[3]);
    }
    #pragma unroll
    for (int ri = 0; ri < 4; ++ri) {
      const int rr = hi * 4 + ri;
      const float iv = sig3(accW[0][ri] * rinv_[ri] + accU[0][ri]);
      const float fv = sig3(accW[1][ri] * rinv_[ri] + accU[1][ri]);
      const float gv = tanh4(accW[2][ri] * rinv_[ri] + accU[2][ri]);
      const float ov = sig3(accW[3][ri] * rinv_[ri] + accU[3][ri]);
      const float cn = fv * cst[ri] + iv * gv;
      const float hv = ov * tanh5(cn);
      *(unsigned short*)((char*)hc + hc_h[ri]) = f2bf(hv);
      *(unsigned short*)((char*)hc + hc_c[ri]) = f2bf(cn);
      *hsP[ri] = hv;
      outHT[(b0 + rr) * DHS + hid] = hv;
      outCT[(b0 + rr) * DHS + hid] = cn;
      hf[rr * 128 + hid] = hv;
    }
  }
  bar_lds();

  // ---- y_pred = h_T @ fc_w + fc_b (waves 0..3, 4 rows each) ----
  if (w < 4) {
    const float fw0 = fcw[l], fw1 = fcw[64 + l];
    const float fb = fcb[0];
    #pragma unroll
    for (int rr = 0; rr < 4; ++rr) {
      const int r = w * 4 + rr;
      float s = hf[r * 128 + l] * fw0 + hf[r * 128 + 64 + l] * fw1;
      #pragma unroll
      for (int msk = 1; msk < 64; msk <<= 1) s += __shfl_xor(s, msk);
      if (l == 0) outY[b0 + r] = s + fb;
    }
  }
}

extern "C" void kernel_launch(void* const* d_in, const int* in_sizes, int n_in,
                              void* d_out, int out_size, void* d_ws, size_t ws_size,
                              hipStream_t stream) {
  const float* X    = (const float*)d_in[0];
  const float* W    = (const float*)d_in[1];
  const float* U    = (const float*)d_in[2];
  const float* bias = (const float*)d_in[3];
  const float* Wa   = (const float*)d_in[4];
  const float* Ua   = (const float*)d_in[5];
  const float* ba   = (const float*)d_in[6];
  const float* Va   = (const float*)d_in[7];
  const float* fcw  = (const float*)d_in[8];
  const float* fcb  = (const float*)d_in[9];
  valstm_kernel<<<16, 512, 0, stream>>>(X, W, U, bias, Wa, Ua, ba, Va, fcw, fcb, (float*)d_out);
}

// Round 10
// 839.679 us; speedup vs baseline: 1.3616x; 1.3616x over previous
//
#include <hip/hip_runtime.h>

// VALSTM: B=256, T=512, IN=64, HS=128, gates=512.
// 16 blocks x 512 threads (8 waves). Block owns 16 batch rows for all T.
// Weights in registers as bf16 B-fragments, pre-scaled by log2e factors.
// Structure = K7 (best: 847us). Per step (3 raw lgkmcnt-only barriers):
//   A: [w<4: attn pre x@Wa + hc@Ua (depth-2 chains) -> tanh -> ta]    bar2
//   B: [w<4: Va^T-GEMM -> exp2 -> u=e*x -> S4 partials]
//      [all: U-GEMM — CRITICAL: consumer U-MFMAs co-resident on each
//       SIMD fill the producer serial-chain stall cycles (r4/r8 lesson:
//       moving them to A regresses 12-35%)]                           bar3
//   C: [all: W-GEMM on u, fold cross-wave rinv, LSTM -> hc;
//       x staging at C-tail (precise vmcnt; r7 lesson)]               bar1
// r6 lesson: softmax denom spans 4 producer waves -> S4 + post-GEMM fold.
// r9: K7 + two local micro-opts only (depth-2 A-chains, v_perm pack2).

#define TSEQ 512
#define NB   256
#define DIN  64
#define DHS  128
#define LOG2E 1.44269504f

typedef short bf16x8 __attribute__((ext_vector_type(8)));
typedef float f32x4  __attribute__((ext_vector_type(4)));
typedef unsigned long long u64;

#define SWZ(off, row) ((off) ^ (((row) & 7) << 4))

__device__ __forceinline__ void bar_lds() {
  asm volatile("s_waitcnt lgkmcnt(0)\n\ts_barrier" ::: "memory");
}

__device__ __forceinline__ float fexp2(float x) { return __builtin_amdgcn_exp2f(x); }
__device__ __forceinline__ float frcp(float x)  { return __builtin_amdgcn_rcpf(x); }
// inputs pre-scaled: x' = log2e*x (sig3), x' = 2*log2e*x (tanh4)
__device__ __forceinline__ float sig3(float x)  { return frcp(1.0f + fexp2(-x)); }
__device__ __forceinline__ float tanh4(float x) { return 1.0f - 2.0f * frcp(1.0f + fexp2(x)); }
__device__ __forceinline__ float tanh5(float y) { return 1.0f - 2.0f * frcp(1.0f + fexp2(2.0f * LOG2E * y)); }

__device__ __forceinline__ unsigned short f2bf(float f) {
  return (unsigned short)((__float_as_uint(f) + 0x8000u) >> 16);
}
// pack two rounded bf16 halves in 3 VALU ops via v_perm_b32
__device__ __forceinline__ unsigned int pack2(float a, float b) {
  return __builtin_amdgcn_perm(__float_as_uint(b) + 0x8000u,
                               __float_as_uint(a) + 0x8000u,
                               0x07060302u);
}
__device__ __forceinline__ float bf2f(unsigned short u) {
  return __uint_as_float(((unsigned int)u) << 16);
}

__global__ __launch_bounds__(512, 2) void valstm_kernel(
    const float* __restrict__ X,  const float* __restrict__ W,  const float* __restrict__ U,
    const float* __restrict__ bias, const float* __restrict__ Wa, const float* __restrict__ Ua,
    const float* __restrict__ ba, const float* __restrict__ Va,
    const float* __restrict__ fcw, const float* __restrict__ fcb,
    float* __restrict__ out)
{
  const int tid = threadIdx.x;
  const int w   = tid >> 6;
  const int l   = tid & 63;
  const int lo  = l & 15;
  const int hi  = l >> 4;
  const int b0  = blockIdx.x * 16;

  // ---- LDS ----
  __shared__ __align__(16) unsigned short hc[16 * 256];      // h|c bf16, stride 512B
  __shared__ __align__(16) unsigned short xbuf2[2][16 * 64]; // x bf16 dbuf, stride 128B
  __shared__ __align__(16) unsigned short ta[16 * 64];       // tanh(attn pre), stride 128B
  __shared__ __align__(16) unsigned short ubuf[16 * 64];     // e*x bf16 (unnormalized), stride 128B
  __shared__ __align__(16) float S4[64];                     // [row][wave] exp partial sums
  __shared__ __align__(16) float hf[16 * 128];               // final-step h f32

  // ---- gate weights as B-fragments, pre-scaled by activation log2e factors ----
  const float sgate[4] = {LOG2E, LOG2E, 2.0f * LOG2E, LOG2E};  // i,f sig | g tanh | o sig
  bf16x8 Uf[4][4];
  bf16x8 Wf[4][2];
  float  biasr[4];
  const int hid = 16 * w + lo;
  #pragma unroll
  for (int g = 0; g < 4; ++g) {
    const int j = g * 128 + hid;
    const float s = sgate[g];
    biasr[g] = bias[j] * s;
    #pragma unroll
    for (int kt = 0; kt < 4; ++kt) {
      bf16x8 v;
      #pragma unroll
      for (int e = 0; e < 8; ++e) { const int k = kt * 32 + hi * 8 + e; v[e] = (short)f2bf(U[k * 512 + j] * s); }
      Uf[g][kt] = v;
    }
    #pragma unroll
    for (int kt = 0; kt < 2; ++kt) {
      bf16x8 v;
      #pragma unroll
      for (int e = 0; e < 8; ++e) { const int k = kt * 32 + hi * 8 + e; v[e] = (short)f2bf(W[k * 512 + j] * s); }
      Wf[g][kt] = v;
    }
  }

  // ---- attention weights (waves 0..3): Wa/Ua/ba *2log2e (tanh), Va *log2e (exp2) ----
  bf16x8 Uaf[8], Waf[2], Vaf[2];
  float  bar = 0.0f;
  if (w < 4) {
    const int ja = 16 * w + lo;
    const float SA = 2.0f * LOG2E;
    bar = ba[ja] * SA;
    #pragma unroll
    for (int kt = 0; kt < 8; ++kt) {
      bf16x8 v;
      #pragma unroll
      for (int e = 0; e < 8; ++e) { const int k = kt * 32 + hi * 8 + e; v[e] = (short)f2bf(Ua[k * 64 + ja] * SA); }
      Uaf[kt] = v;
    }
    #pragma unroll
    for (int kt = 0; kt < 2; ++kt) {
      bf16x8 v;
      #pragma unroll
      for (int e = 0; e < 8; ++e) { const int k = kt * 32 + hi * 8 + e; v[e] = (short)f2bf(Wa[k * 64 + ja] * SA); }
      Waf[kt] = v;
    }
    #pragma unroll
    for (int kt = 0; kt < 2; ++kt) {
      bf16x8 v;
      #pragma unroll
      for (int e = 0; e < 8; ++e) { const int k = kt * 32 + hi * 8 + e; v[e] = (short)f2bf(Va[k * 64 + ja] * LOG2E); }
      Vaf[kt] = v;
    }
  }

  // ---- hoisted swizzled LDS byte-offsets ----
  int haf_off[4], caf_off[4], xa_off[2];
  #pragma unroll
  for (int kt = 0; kt < 4; ++kt) {
    haf_off[kt] = SWZ(lo * 512 + (kt * 32 + hi * 8) * 2, lo);
    caf_off[kt] = SWZ(lo * 512 + ((kt + 4) * 32 + hi * 8) * 2, lo);
  }
  #pragma unroll
  for (int kt = 0; kt < 2; ++kt)
    xa_off[kt] = SWZ(lo * 128 + (kt * 32 + hi * 8) * 2, lo);   // x, ta, u fragment reads
  int ta_st[4], hc_h[4], hc_c[4];
  #pragma unroll
  for (int ri = 0; ri < 4; ++ri) {
    const int rr = hi * 4 + ri;
    ta_st[ri] = SWZ(rr * 128 + (16 * w + lo) * 2, rr);
    hc_h[ri]  = SWZ(rr * 512 + hid * 2, rr);
    hc_c[ri]  = SWZ(rr * 512 + (128 + hid) * 2, rr);
  }
  const int uq_off = SWZ(lo * 128 + (16 * w + hi * 4) * 2, lo); // producer u/x slots

  // ---- zero h,c ----
  *(f32x4*)((char*)hc + tid * 16) = (f32x4){0.f, 0.f, 0.f, 0.f};

  // ---- x staging (all threads, 2 cols each, C-tail placement) ----
  const int xr = tid >> 5;
  const int xc = (tid & 31) * 2;
  const int xst_off = SWZ(xr * 128 + xc * 2, xr);
  const float* xptr = X + (size_t)(b0 + xr) * TSEQ * DIN + xc;
  {
    const float2 v0 = *(const float2*)(xptr + 0 * DIN);
    *(unsigned int*)((char*)xbuf2[0] + xst_off) = pack2(v0.x, v0.y);
  }
  float2 xf = *(const float2*)(xptr + 1 * DIN);

  float cst[4] = {0.f, 0.f, 0.f, 0.f};

  float* outY  = out;
  float* outHS = out + 256;
  float* outHT = out + 256 + (size_t)NB * TSEQ * DHS;
  float* outCT = outHT + NB * DHS;
  float* outAL = outCT + NB * DHS;

  float* hsP[4];
  #pragma unroll
  for (int ri = 0; ri < 4; ++ri)
    hsP[ri] = outHS + (size_t)(b0 + hi * 4 + ri) * TSEQ * DHS + hid;

  bar_lds();

  #pragma unroll 1
  for (int t = 0; t < TSEQ - 1; ++t) {
    const int xoff = (t & 1) << 11;

    bf16x8 haf[4];
    #pragma unroll
    for (int kt = 0; kt < 4; ++kt)
      haf[kt] = *(const bf16x8*)((const char*)hc + haf_off[kt]);

    // ---- A: attention pre-activation (producers only, depth-2 chains) ----
    if (w < 4) {
      __builtin_amdgcn_s_setprio(1);
      f32x4 aa  = (f32x4){bar, bar, bar, bar};
      f32x4 ah0 = (f32x4){0.f, 0.f, 0.f, 0.f};
      f32x4 ah1 = (f32x4){0.f, 0.f, 0.f, 0.f};
      f32x4 ac0 = (f32x4){0.f, 0.f, 0.f, 0.f};
      f32x4 ac1 = (f32x4){0.f, 0.f, 0.f, 0.f};
      #pragma unroll
      for (int kt = 0; kt < 2; ++kt) {
        bf16x8 xa = *(const bf16x8*)((const char*)xbuf2[0] + xoff + xa_off[kt]);
        aa = __builtin_amdgcn_mfma_f32_16x16x32_bf16(xa, Waf[kt], aa, 0, 0, 0);
      }
      ah0 = __builtin_amdgcn_mfma_f32_16x16x32_bf16(haf[0], Uaf[0], ah0, 0, 0, 0);
      ah0 = __builtin_amdgcn_mfma_f32_16x16x32_bf16(haf[1], Uaf[1], ah0, 0, 0, 0);
      ah1 = __builtin_amdgcn_mfma_f32_16x16x32_bf16(haf[2], Uaf[2], ah1, 0, 0, 0);
      ah1 = __builtin_amdgcn_mfma_f32_16x16x32_bf16(haf[3], Uaf[3], ah1, 0, 0, 0);
      {
        bf16x8 ca0 = *(const bf16x8*)((const char*)hc + caf_off[0]);
        bf16x8 ca1 = *(const bf16x8*)((const char*)hc + caf_off[1]);
        ac0 = __builtin_amdgcn_mfma_f32_16x16x32_bf16(ca0, Uaf[4], ac0, 0, 0, 0);
        ac0 = __builtin_amdgcn_mfma_f32_16x16x32_bf16(ca1, Uaf[5], ac0, 0, 0, 0);
        bf16x8 ca2 = *(const bf16x8*)((const char*)hc + caf_off[2]);
        bf16x8 ca3 = *(const bf16x8*)((const char*)hc + caf_off[3]);
        ac1 = __builtin_amdgcn_mfma_f32_16x16x32_bf16(ca2, Uaf[6], ac1, 0, 0, 0);
        ac1 = __builtin_amdgcn_mfma_f32_16x16x32_bf16(ca3, Uaf[7], ac1, 0, 0, 0);
      }
      const f32x4 pre = ((aa + ah0) + (ah1 + ac0)) + ac1;   // pre-scaled by 2log2e
      #pragma unroll
      for (int ri = 0; ri < 4; ++ri)
        *(unsigned short*)((char*)ta + ta_st[ri]) = f2bf(tanh4(pre[ri]));
    }
    bar_lds();  // bar2: ta ready

    // ---- B: producers Va->exp2->u + S4 partials ;
    //         ALL waves U-GEMM (consumer MFMAs hide producer stalls) ----
    if (w < 4) {
      f32x4 av = (f32x4){0.f, 0.f, 0.f, 0.f};
      #pragma unroll
      for (int kt = 0; kt < 2; ++kt) {
        bf16x8 tf = *(const bf16x8*)((const char*)ta + xa_off[kt]);
        av = __builtin_amdgcn_mfma_f32_16x16x32_bf16(Vaf[kt], tf, av, 0, 0, 0);
      }
      f32x4 ev;
      #pragma unroll
      for (int ri = 0; ri < 4; ++ri) ev[ri] = fexp2(av[ri]);   // Va pre-scaled
      const u64 xq = *(const u64*)((const char*)xbuf2[0] + xoff + uq_off);
      const unsigned int p0 = pack2(ev[0] * bf2f((unsigned short)xq),
                                    ev[1] * bf2f((unsigned short)(xq >> 16)));
      const unsigned int p1 = pack2(ev[2] * bf2f((unsigned short)(xq >> 32)),
                                    ev[3] * bf2f((unsigned short)(xq >> 48)));
      *(u64*)((char*)ubuf + uq_off) = (u64)p0 | ((u64)p1 << 32);
      float ps = ev[0] + ev[1] + ev[2] + ev[3];
      ps += __shfl_xor(ps, 16);
      ps += __shfl_xor(ps, 32);
      if (hi == 0) S4[lo * 4 + w] = ps;   // wave partial (16 of 64 cols)
      __builtin_amdgcn_s_setprio(0);
    }
    f32x4 accU[4];
    #pragma unroll
    for (int g = 0; g < 4; ++g) {
      accU[g] = (f32x4){biasr[g], biasr[g], biasr[g], biasr[g]};
      #pragma unroll
      for (int kt = 0; kt < 4; ++kt)
        accU[g] = __builtin_amdgcn_mfma_f32_16x16x32_bf16(haf[kt], Uf[g][kt], accU[g], 0, 0, 0);
    }
    bar_lds();  // bar3: u + S4 ready

    // ---- C: W-GEMM on u, fold cross-wave rinv, LSTM update ----
    f32x4 accW[4];
    #pragma unroll
    for (int g = 0; g < 4; ++g) accW[g] = (f32x4){0.f, 0.f, 0.f, 0.f};
    #pragma unroll
    for (int kt = 0; kt < 2; ++kt) {
      const bf16x8 uf = *(const bf16x8*)((const char*)ubuf + xa_off[kt]);
      #pragma unroll
      for (int g = 0; g < 4; ++g)
        accW[g] = __builtin_amdgcn_mfma_f32_16x16x32_bf16(uf, Wf[g][kt], accW[g], 0, 0, 0);
    }
    float rinv_[4];
    #pragma unroll
    for (int ri = 0; ri < 4; ++ri) {
      const f32x4 s4v = *(const f32x4*)(S4 + (hi * 4 + ri) * 4);
      rinv_[ri] = frcp(s4v[0] + s4v[1] + s4v[2] + s4v[3]);
    }
    #pragma unroll
    for (int ri = 0; ri < 4; ++ri) {
      const float iv = sig3(accW[0][ri] * rinv_[ri] + accU[0][ri]);
      const float fv = sig3(accW[1][ri] * rinv_[ri] + accU[1][ri]);
      const float gv = tanh4(accW[2][ri] * rinv_[ri] + accU[2][ri]);
      const float ov = sig3(accW[3][ri] * rinv_[ri] + accU[3][ri]);
      const float cn = fv * cst[ri] + iv * gv;
      const float hv = ov * tanh5(cn);
      cst[ri] = cn;
      *(unsigned short*)((char*)hc + hc_h[ri]) = f2bf(hv);
      *(unsigned short*)((char*)hc + hc_c[ri]) = f2bf(cn);
      *hsP[ri] = hv;                      // fire-and-forget
      hsP[ri] += DHS;
    }

    // ---- stage x(t+1), prefetch x(min(t+2, T-1)) — C-tail, precise vmcnt ----
    {
      *(unsigned int*)((char*)xbuf2[0] + (((t + 1) & 1) << 11) + xst_off) = pack2(xf.x, xf.y);
      const int tn = (t + 2 < TSEQ) ? t + 2 : TSEQ - 1;
      xf = *(const float2*)(xptr + tn * DIN);
    }
    bar_lds();  // bar1
  }

  // ==== peeled final step t = TSEQ-1 ====
  {
    const int xoff = ((TSEQ - 1) & 1) << 11;

    bf16x8 haf[4];
    #pragma unroll
    for (int kt = 0; kt < 4; ++kt)
      haf[kt] = *(const bf16x8*)((const char*)hc + haf_off[kt]);

    if (w < 4) {
      f32x4 aa = (f32x4){bar, bar, bar, bar};
      f32x4 ah = (f32x4){0.f, 0.f, 0.f, 0.f};
      f32x4 ac = (f32x4){0.f, 0.f, 0.f, 0.f};
      #pragma unroll
      for (int kt = 0; kt < 2; ++kt) {
        bf16x8 xa = *(const bf16x8*)((const char*)xbuf2[0] + xoff + xa_off[kt]);
        aa = __builtin_amdgcn_mfma_f32_16x16x32_bf16(xa, Waf[kt], aa, 0, 0, 0);
      }
      #pragma unroll
      for (int kt = 0; kt < 4; ++kt)
        ah = __builtin_amdgcn_mfma_f32_16x16x32_bf16(haf[kt], Uaf[kt], ah, 0, 0, 0);
      #pragma unroll
      for (int kt = 0; kt < 4; ++kt) {
        bf16x8 ca = *(const bf16x8*)((const char*)hc + caf_off[kt]);
        ac = __builtin_amdgcn_mfma_f32_16x16x32_bf16(ca, Uaf[kt + 4], ac, 0, 0, 0);
      }
      const f32x4 pre = aa + ah + ac;
      #pragma unroll
      for (int ri = 0; ri < 4; ++ri)
        *(unsigned short*)((char*)ta + ta_st[ri]) = f2bf(tanh4(pre[ri]));
    }
    bar_lds();

    f32x4 evP = (f32x4){0.f, 0.f, 0.f, 0.f};
    if (w < 4) {
      f32x4 av = (f32x4){0.f, 0.f, 0.f, 0.f};
      #pragma unroll
      for (int kt = 0; kt < 2; ++kt) {
        bf16x8 tf = *(const bf16x8*)((const char*)ta + xa_off[kt]);
        av = __builtin_amdgcn_mfma_f32_16x16x32_bf16(Vaf[kt], tf, av, 0, 0, 0);
      }
      #pragma unroll
      for (int ri = 0; ri < 4; ++ri) evP[ri] = fexp2(av[ri]);
      const u64 xq = *(const u64*)((const char*)xbuf2[0] + xoff + uq_off);
      const unsigned int p0 = pack2(evP[0] * bf2f((unsigned short)xq),
                                    evP[1] * bf2f((unsigned short)(xq >> 16)));
      const unsigned int p1 = pack2(evP[2] * bf2f((unsigned short)(xq >> 32)),
                                    evP[3] * bf2f((unsigned short)(xq >> 48)));
      *(u64*)((char*)ubuf + uq_off) = (u64)p0 | ((u64)p1 << 32);
      float ps = evP[0] + evP[1] + evP[2] + evP[3];
      ps += __shfl_xor(ps, 16);
      ps += __shfl_xor(ps, 32);
      if (hi == 0) S4[lo * 4 + w] = ps;
    }
    f32x4 accU[4];
    #pragma unroll
    for (int g = 0; g < 4; ++g) {
      accU[g] = (f32x4){biasr[g], biasr[g], biasr[g], biasr[g]};
      #pragma unroll
      for (int kt = 0; kt < 4; ++kt)
        accU[g] = __builtin_amdgcn_mfma_f32_16x16x32_bf16(haf[kt], Uf[g][kt], accU[g], 0, 0, 0);
    }
    bar_lds();

    // alpha output: cross-wave rinv for batch row lo
    if (w < 4) {
      const f32x4 s4v = *(const f32x4*)(S4 + lo * 4);
      const float rA = frcp(s4v[0] + s4v[1] + s4v[2] + s4v[3]);
      *(f32x4*)(outAL + (b0 + lo) * 64 + 16 * w + hi * 4) =
          (f32x4){evP[0] * rA, evP[1] * rA, evP[2] * rA, evP[3] * rA};
    }

    f32x4 accW[4];
    #pragma unroll
    for (int g = 0; g < 4; ++g) accW[g] = (f32x4){0.f, 0.f, 0.f, 0.f};
    #pragma unroll
    for (int kt = 0; kt < 2; ++kt) {
      const bf16x8 uf = *(const bf16x8*)((const char*)ubuf + xa_off[kt]);
      #pragma unroll
      for (int g = 0; g < 4; ++g)
        accW[g] = __builtin_amdgcn_mfma_f32_16x16x32_bf16(uf, Wf[g][kt], accW[g], 0, 0, 0);
    }
    float rinv_[4];
    #pragma unroll
    for (int ri = 0; ri < 4; ++ri) {
      const f32x4 s4v = *(const f32x4*)(S4 + (hi * 4 + ri) * 4);
      rinv_[ri] = frcp(s4v[0] + s4v[1] + s4v[2] + s4v[3]);
    }
    #pragma unroll
    for (int ri = 0; ri < 4; ++ri) {
      const int rr = hi * 4 + ri;
      const float iv = sig3(accW[0][ri] * rinv_[ri] + accU[0][ri]);
      const float fv = sig3(accW[1][ri] * rinv_[ri] + accU[1][ri]);
      const float gv = tanh4(accW[2][ri] * rinv_[ri] + accU[2][ri]);
      const float ov = sig3(accW[3][ri] * rinv_[ri] + accU[3][ri]);
      const float cn = fv * cst[ri] + iv * gv;
      const float hv = ov * tanh5(cn);
      *(unsigned short*)((char*)hc + hc_h[ri]) = f2bf(hv);
      *(unsigned short*)((char*)hc + hc_c[ri]) = f2bf(cn);
      *hsP[ri] = hv;
      outHT[(b0 + rr) * DHS + hid] = hv;
      outCT[(b0 + rr) * DHS + hid] = cn;
      hf[rr * 128 + hid] = hv;
    }
  }
  bar_lds();

  // ---- y_pred = h_T @ fc_w + fc_b (waves 0..3, 4 rows each) ----
  if (w < 4) {
    const float fw0 = fcw[l], fw1 = fcw[64 + l];
    const float fb = fcb[0];
    #pragma unroll
    for (int rr = 0; rr < 4; ++rr) {
      const int r = w * 4 + rr;
      float s = hf[r * 128 + l] * fw0 + hf[r * 128 + 64 + l] * fw1;
      #pragma unroll
      for (int msk = 1; msk < 64; msk <<= 1) s += __shfl_xor(s, msk);
      if (l == 0) outY[b0 + r] = s + fb;
    }
  }
}

extern "C" void kernel_launch(void* const* d_in, const int* in_sizes, int n_in,
                              void* d_out, int out_size, void* d_ws, size_t ws_size,
                              hipStream_t stream) {
  const float* X    = (const float*)d_in[0];
  const float* W    = (const float*)d_in[1];
  const float* U    = (const float*)d_in[2];
  const float* bias = (const float*)d_in[3];
  const float* Wa   = (const float*)d_in[4];
  const float* Ua   = (const float*)d_in[5];
  const float* ba   = (const float*)d_in[6];
  const float* Va   = (const float*)d_in[7];
  const float* fcw  = (const float*)d_in[8];
  const float* fcb  = (const float*)d_in[9];
  valstm_kernel<<<16, 512, 0, stream>>>(X, W, U, bias, Wa, Ua, ba, Va, fcw, fcb, (float*)d_out);
}